// Round 4
// baseline (618.109 us; speedup 1.0000x reference)
//
#include <hip/hip_runtime.h>

// InterestEvolve: attention-modulated GRU scan. B=2048, T=200, D=128, U=128.
//
// R4 = R3 with the compile fix (pkbf2 via integer packing, no __hip_bfloat162).
// Transposed MFMA mapping — gatecols = M (A = weights, in regs),
// batch = N (B = h/x/rh frags from LDS). C/D: col=batch, row=gatecol, so
// rh/h LDS publishes are single ds_write_b64 (4 packed bf16) per tile, the
// attention factor is one scalar per thread, and the final store is dwordx4.
// Unpadded XOR-swizzled LDS (chunk ^= row&7) = conflict-free baseline
// structure for both b128 reads and staging writes.

#define T_LEN 200
#define D_DIM 128
#define U_DIM 128
#define BM    16
#define CH    12    // staged timesteps per chunk; 17 chunks (last = 8)

typedef __attribute__((ext_vector_type(8))) short bf16x8;
typedef __attribute__((ext_vector_type(4))) float f32x4;

static __device__ __forceinline__ unsigned short f2bf(float f) {
    unsigned int u = __builtin_bit_cast(unsigned int, f);
    u += 0x7fffu + ((u >> 16) & 1u);       // round-to-nearest-even
    return (unsigned short)(u >> 16);
}
static __device__ __forceinline__ bf16x8 pack8(float4 lo, float4 hi) {
    bf16x8 v;
    v[0] = (short)f2bf(lo.x); v[1] = (short)f2bf(lo.y);
    v[2] = (short)f2bf(lo.z); v[3] = (short)f2bf(lo.w);
    v[4] = (short)f2bf(hi.x); v[5] = (short)f2bf(hi.y);
    v[6] = (short)f2bf(hi.z); v[7] = (short)f2bf(hi.w);
    return v;
}
static __device__ __forceinline__ unsigned int pkbf2(float a, float b) {
    return (unsigned int)f2bf(a) | ((unsigned int)f2bf(b) << 16);
}
static __device__ __forceinline__ float fast_exp2(float x) {
#if __has_builtin(__builtin_amdgcn_exp2f)
    return __builtin_amdgcn_exp2f(x);
#else
    return exp2f(x);
#endif
}
static __device__ __forceinline__ float fast_rcp(float x) {
#if __has_builtin(__builtin_amdgcn_rcpf)
    return __builtin_amdgcn_rcpf(x);
#else
    return 1.0f / x;
#endif
}
// XOR-swizzled element offset of 16B chunk `c` in row `row` of a [rows][128] bf16 array
static __device__ __forceinline__ int swz(int row, int c) {
    return row * 128 + (((c ^ (row & 7))) << 3);
}

__global__ __launch_bounds__(256, 1)
void gru_scan_kernel(const float* __restrict__ X,    // (B,T,D)
                     const float* __restrict__ Att,  // (B,T,1)
                     const float* __restrict__ Wu, const float* __restrict__ bu,
                     const float* __restrict__ Wr, const float* __restrict__ br,
                     const float* __restrict__ Wh, const float* __restrict__ bh,
                     float* __restrict__ out)        // (B,U)
{
    __shared__ __align__(16) unsigned short x_sm[CH * BM * 128];  // 48 KB, swizzled
    __shared__ __align__(16) unsigned short h_bf[BM * 128];       // 4 KB, swizzled
    __shared__ __align__(16) unsigned short rh_bf[BM * 128];      // 4 KB, swizzled
    __shared__ float a_sm[CH * BM];                               // 768 B

    const int tid  = threadIdx.x;
    const int wave = tid >> 6;
    const int lane = tid & 63;
    const int q    = lane >> 4;   // quad 0..3
    const int ln   = lane & 15;   // = batch row within tile (N), = weight-row (M) for A-frags
    const int b0   = blockIdx.x * BM;

    const float INVLN2 = 1.4426950408889634f;

    // ---- Weight A-fragments in registers (bf16, ln2-prescaled). ----
    // A-frag (16x16x32): lane holds row m = lane&15 (= gatecol within tile),
    // k = 8*q + j. Element = W[k_global][tilebase + ln].
    // GEMM1 k: [h(0:128)|x(128:256)] rows of Wu/Wr. GEMM2 k: [x|r*h] rows of Wh.
    bf16x8 wu[2][8], wr[2][8], wh[2][8];
    f32x4 nbu[2], nbr[2], bh2[2];   // per-gatecol biases for rows 4q+0..3
    #pragma unroll
    for (int nt = 0; nt < 2; ++nt) {
        const int tb = 32 * wave + 16 * nt;     // tile base gatecol
        const int c  = tb + ln;                 // A-frag weight column
        const f32x4 bu4 = *(const f32x4*)&bu[tb + 4 * q];
        const f32x4 br4 = *(const f32x4*)&br[tb + 4 * q];
        const f32x4 bh4 = *(const f32x4*)&bh[tb + 4 * q];
        #pragma unroll
        for (int r = 0; r < 4; ++r) {
            nbu[nt][r] = -bu4[r] * INVLN2;
            nbr[nt][r] = -br4[r] * INVLN2;
            bh2[nt][r] = 2.0f * bh4[r] * INVLN2;
        }
        #pragma unroll
        for (int kt = 0; kt < 8; ++kt) {
            const int k0 = 32 * kt + 8 * q;
            bf16x8 vu, vr, vh;
            #pragma unroll
            for (int j = 0; j < 8; ++j) {
                vu[j] = (short)f2bf(Wu[(k0 + j) * U_DIM + c] * -INVLN2);
                vr[j] = (short)f2bf(Wr[(k0 + j) * U_DIM + c] * -INVLN2);
                vh[j] = (short)f2bf(Wh[(k0 + j) * U_DIM + c] * (2.0f * INVLN2));
            }
            wu[nt][kt] = vu; wr[nt][kt] = vr; wh[nt][kt] = vh;
        }
    }

    // ---- init ----
    float hreg[2][4];   // fp32 h: batch = ln, gatecol = 32*wave + 16*nt + 4q + r
    #pragma unroll
    for (int nt = 0; nt < 2; ++nt)
        #pragma unroll
        for (int r = 0; r < 4; ++r) hreg[nt][r] = 0.0f;
    {
        unsigned int* hz = (unsigned int*)h_bf;
        #pragma unroll
        for (int i = 0; i < (BM * 128 / 2) / 256; ++i) hz[tid + 256 * i] = 0;
    }

    const int brs = tid >> 4;   // staging: batch row
    const int cs  = tid & 15;   // staging: 16B chunk within row

    int t0 = 0;
    for (int ch = 0; ch < (T_LEN + CH - 1) / CH; ++ch) {
        const int L = (t0 + CH <= T_LEN) ? CH : (T_LEN - t0);

        // ---- stage chunk: iteration w stages timestep t0+w ----
        for (int w = 0; w < L; ++w) {
            const float* src = X + ((size_t)(b0 + brs) * T_LEN + (t0 + w)) * D_DIM + cs * 8;
            float4 lo = *(const float4*)(src);
            float4 hi = *(const float4*)(src + 4);
            *(bf16x8*)&x_sm[swz(w * BM + brs, cs)] = pack8(lo, hi);
        }
        if (tid < BM * CH && (tid >> 4) < L)
            a_sm[tid] = Att[(size_t)(b0 + (tid & 15)) * T_LEN + t0 + (tid >> 4)];
        __syncthreads();

        for (int s = 0; s < L; ++s) {
            // ---------- phase A: B-frag loads + GEMM1 + GEMM2 x-part ----------
            bf16x8 hf[4], xf[4];
            #pragma unroll
            for (int kt = 0; kt < 4; ++kt) {
                hf[kt] = *(const bf16x8*)&h_bf[swz(ln, 4 * kt + q)];
                xf[kt] = *(const bf16x8*)&x_sm[swz(s * BM + ln, 4 * kt + q)];
            }
            const float a_att = a_sm[s * BM + ln];

            f32x4 accr[2], accu[2], acch[2];
            #pragma unroll
            for (int nt = 0; nt < 2; ++nt) {
                accr[nt] = (f32x4)0.0f; accu[nt] = (f32x4)0.0f; acch[nt] = (f32x4)0.0f;
            }
            #pragma unroll
            for (int kt = 0; kt < 4; ++kt)
                #pragma unroll
                for (int nt = 0; nt < 2; ++nt) {
                    accr[nt] = __builtin_amdgcn_mfma_f32_16x16x32_bf16(wr[nt][kt], hf[kt], accr[nt], 0, 0, 0);
                    accu[nt] = __builtin_amdgcn_mfma_f32_16x16x32_bf16(wu[nt][kt], hf[kt], accu[nt], 0, 0, 0);
                    acch[nt] = __builtin_amdgcn_mfma_f32_16x16x32_bf16(wh[nt][kt], xf[kt], acch[nt], 0, 0, 0);
                }
            #pragma unroll
            for (int kt = 0; kt < 4; ++kt)
                #pragma unroll
                for (int nt = 0; nt < 2; ++nt) {
                    accr[nt] = __builtin_amdgcn_mfma_f32_16x16x32_bf16(wr[nt][kt + 4], xf[kt], accr[nt], 0, 0, 0);
                    accu[nt] = __builtin_amdgcn_mfma_f32_16x16x32_bf16(wu[nt][kt + 4], xf[kt], accu[nt], 0, 0, 0);
                }

            // ---------- phase B: r sigmoid; r*h -> LDS (b64, 4 packed bf16) ----------
            #pragma unroll
            for (int nt = 0; nt < 2; ++nt) {
                float rh[4];
                #pragma unroll
                for (int r = 0; r < 4; ++r) {
                    float zr = accr[nt][r] + nbr[nt][r];                // = -z_r/ln2
                    float rv = fast_rcp(1.0f + fast_exp2(zr));          // sigmoid
                    rh[r] = rv * hreg[nt][r];
                }
                uint2 wv; wv.x = pkbf2(rh[0], rh[1]); wv.y = pkbf2(rh[2], rh[3]);
                const int c = 4 * wave + 2 * nt + (q >> 1);
                *(uint2*)&rh_bf[ln * 128 + ((c ^ (ln & 7)) << 3) + (q & 1) * 4] = wv;
            }
            __syncthreads();   // rh handoff

            // ---------- phase C: GEMM2 rh-part; u-gate sigmoid overlaps MFMA ----------
            bf16x8 rf[4];
            #pragma unroll
            for (int kt = 0; kt < 4; ++kt)
                rf[kt] = *(const bf16x8*)&rh_bf[swz(ln, 4 * kt + q)];

            float uq[2][4];
            #pragma unroll
            for (int nt = 0; nt < 2; ++nt)
                #pragma unroll
                for (int r = 0; r < 4; ++r) {
                    float zu = accu[nt][r] + nbu[nt][r];                // = -z_u/ln2
                    float u  = fast_rcp(1.0f + fast_exp2(zu));          // sigmoid
                    uq[nt][r] = u * a_att;                              // attention-modulated
                }
            #pragma unroll
            for (int kt = 0; kt < 4; ++kt)
                #pragma unroll
                for (int nt = 0; nt < 2; ++nt)
                    acch[nt] = __builtin_amdgcn_mfma_f32_16x16x32_bf16(wh[nt][kt + 4], rf[kt], acch[nt], 0, 0, 0);

            // ---------- phase D: tanh, h update (fp32 regs), publish h (b64) ----------
            #pragma unroll
            for (int nt = 0; nt < 2; ++nt) {
                #pragma unroll
                for (int r = 0; r < 4; ++r) {
                    float z  = acch[nt][r] + bh2[nt][r];                    // = 2*z_h/ln2
                    float hh = 1.0f - 2.0f * fast_rcp(1.0f + fast_exp2(z)); // tanh
                    float ho = hreg[nt][r];
                    hreg[nt][r] = ho + uq[nt][r] * (hh - ho);               // u*hh + (1-u)*h
                }
                uint2 wv; wv.x = pkbf2(hreg[nt][0], hreg[nt][1]);
                wv.y = pkbf2(hreg[nt][2], hreg[nt][3]);
                const int c = 4 * wave + 2 * nt + (q >> 1);
                *(uint2*)&h_bf[ln * 128 + ((c ^ (ln & 7)) << 3) + (q & 1) * 4] = wv;
            }
            __syncthreads();   // h handoff to next step / chunk restage
        }
        t0 += CH;
    }

    // ---- store h_final: 4 consecutive gatecols per thread -> dwordx4 ----
    #pragma unroll
    for (int nt = 0; nt < 2; ++nt) {
        f32x4 v;
        #pragma unroll
        for (int r = 0; r < 4; ++r) v[r] = hreg[nt][r];
        *(f32x4*)&out[(size_t)(b0 + ln) * U_DIM + 32 * wave + 16 * nt + 4 * q] = v;
    }
}

extern "C" void kernel_launch(void* const* d_in, const int* in_sizes, int n_in,
                              void* d_out, int out_size, void* d_ws, size_t ws_size,
                              hipStream_t stream) {
    const float* X   = (const float*)d_in[0];
    const float* Att = (const float*)d_in[1];
    const float* Wu  = (const float*)d_in[2];
    const float* bu  = (const float*)d_in[3];
    const float* Wr  = (const float*)d_in[4];
    const float* br  = (const float*)d_in[5];
    const float* Wh  = (const float*)d_in[6];
    const float* bh  = (const float*)d_in[7];
    float* out = (float*)d_out;

    gru_scan_kernel<<<dim3(2048 / BM), dim3(256), 0, stream>>>(
        X, Att, Wu, bu, Wr, br, Wh, bh, out);
}

// Round 5
// 489.364 us; speedup vs baseline: 1.2631x; 1.2631x over previous
//
#include <hip/hip_runtime.h>

// InterestEvolve: attention-modulated GRU scan. B=2048, T=200, D=128, U=128.
//
// R5: occupancy fix. R4 ran 1 wave/SIMD (4 waves/block) -> every latency
// exposed (measured 4950 cyc/step vs ~1400 pipe-bound). Now 512 threads =
// 8 waves = 2 waves/SIMD; each wave owns 16 gatecols (one 16x16 M-tile),
// half the per-wave VALU/MFMA, same per-SIMD pipe load, stalls overlap.
// Transposed MFMA mapping kept: gatecols = M (A = weights in regs, 96 VGPR),
// batch = N (B-frags from LDS). Staging: all 12 global float4 loads issued
// before packing (one HBM latency per 12-step chunk), clamped indices.

#define T_LEN 200
#define D_DIM 128
#define U_DIM 128
#define BM    16
#define CH    12    // staged timesteps per chunk; 17 chunks (last = 8)

typedef __attribute__((ext_vector_type(8))) short bf16x8;
typedef __attribute__((ext_vector_type(4))) float f32x4;

static __device__ __forceinline__ unsigned short f2bf(float f) {
    unsigned int u = __builtin_bit_cast(unsigned int, f);
    u += 0x7fffu + ((u >> 16) & 1u);       // round-to-nearest-even
    return (unsigned short)(u >> 16);
}
static __device__ __forceinline__ bf16x8 pack8(float4 lo, float4 hi) {
    bf16x8 v;
    v[0] = (short)f2bf(lo.x); v[1] = (short)f2bf(lo.y);
    v[2] = (short)f2bf(lo.z); v[3] = (short)f2bf(lo.w);
    v[4] = (short)f2bf(hi.x); v[5] = (short)f2bf(hi.y);
    v[6] = (short)f2bf(hi.z); v[7] = (short)f2bf(hi.w);
    return v;
}
static __device__ __forceinline__ unsigned int pkbf2(float a, float b) {
    return (unsigned int)f2bf(a) | ((unsigned int)f2bf(b) << 16);
}
static __device__ __forceinline__ float fast_exp2(float x) {
#if __has_builtin(__builtin_amdgcn_exp2f)
    return __builtin_amdgcn_exp2f(x);
#else
    return exp2f(x);
#endif
}
static __device__ __forceinline__ float fast_rcp(float x) {
#if __has_builtin(__builtin_amdgcn_rcpf)
    return __builtin_amdgcn_rcpf(x);
#else
    return 1.0f / x;
#endif
}
// XOR-swizzled element offset of 16B chunk `c` in row `row` of a [rows][128] bf16 array
static __device__ __forceinline__ int swz(int row, int c) {
    return row * 128 + ((c ^ (row & 7)) << 3);
}

__global__ __launch_bounds__(512, 2)
void gru_scan_kernel(const float* __restrict__ X,    // (B,T,D)
                     const float* __restrict__ Att,  // (B,T,1)
                     const float* __restrict__ Wu, const float* __restrict__ bu,
                     const float* __restrict__ Wr, const float* __restrict__ br,
                     const float* __restrict__ Wh, const float* __restrict__ bh,
                     float* __restrict__ out)        // (B,U)
{
    __shared__ __align__(16) unsigned short x_sm[CH * BM * 128];  // 48 KB, swizzled
    __shared__ __align__(16) unsigned short h_bf[BM * 128];       // 4 KB, swizzled
    __shared__ __align__(16) unsigned short rh_bf[BM * 128];      // 4 KB, swizzled
    __shared__ float a_sm[CH * BM];                               // 768 B

    const int tid  = threadIdx.x;
    const int wave = tid >> 6;    // 0..7, owns gatecols [16*wave, 16*wave+16)
    const int lane = tid & 63;
    const int q    = lane >> 4;   // quad 0..3
    const int ln   = lane & 15;   // batch row (N) / weight col row-index (M side uses lane&15 too)
    const int b0   = blockIdx.x * BM;

    const float INVLN2 = 1.4426950408889634f;

    // ---- Weight A-fragments (one 16-col tile per wave), bf16, ln2-prescaled.
    // A-frag (16x16x32): lane holds row m = lane&15 (gatecol within tile),
    // k = 8*q + j. Element = W[k_global][16*wave + ln].
    // GEMM1 k: [h(0:128)|x(128:256)] rows of Wu/Wr. GEMM2 k: [x|r*h] rows of Wh.
    bf16x8 wu[8], wr[8], wh[8];
    f32x4 nbu, nbr, bh2;   // per-gatecol biases for rows 4q+0..3
    {
        const int tb = 16 * wave;
        const int c  = tb + ln;
        const f32x4 bu4 = *(const f32x4*)&bu[tb + 4 * q];
        const f32x4 br4 = *(const f32x4*)&br[tb + 4 * q];
        const f32x4 bh4 = *(const f32x4*)&bh[tb + 4 * q];
        #pragma unroll
        for (int r = 0; r < 4; ++r) {
            nbu[r] = -bu4[r] * INVLN2;
            nbr[r] = -br4[r] * INVLN2;
            bh2[r] = 2.0f * bh4[r] * INVLN2;
        }
        #pragma unroll
        for (int kt = 0; kt < 8; ++kt) {
            const int k0 = 32 * kt + 8 * q;
            bf16x8 vu, vr, vh;
            #pragma unroll
            for (int j = 0; j < 8; ++j) {
                vu[j] = (short)f2bf(Wu[(k0 + j) * U_DIM + c] * -INVLN2);
                vr[j] = (short)f2bf(Wr[(k0 + j) * U_DIM + c] * -INVLN2);
                vh[j] = (short)f2bf(Wh[(k0 + j) * U_DIM + c] * (2.0f * INVLN2));
            }
            wu[kt] = vu; wr[kt] = vr; wh[kt] = vh;
        }
    }

    // ---- init ----
    float hreg[4];   // fp32 h: batch = ln, gatecol = 16*wave + 4q + r
    #pragma unroll
    for (int r = 0; r < 4; ++r) hreg[r] = 0.0f;
    {
        unsigned int* hz = (unsigned int*)h_bf;
        if (tid < BM * 128 / 2 - 512) hz[tid + 512] = 0;
        hz[tid] = 0;
    }

    // staging map: 512 threads cover 2 steps per iteration
    const int s2   = tid >> 8;          // 0/1: which of the 2 steps this iter
    const int srow = (tid >> 4) & 15;   // batch row
    const int cs   = tid & 15;          // 16B chunk within 256B row
    const float* xbase = X + (size_t)(b0 + srow) * T_LEN * D_DIM + cs * 8;

    int t0 = 0;
    for (int ch = 0; ch < (T_LEN + CH - 1) / CH; ++ch) {
        const int L = (t0 + CH <= T_LEN) ? CH : (T_LEN - t0);

        // ---- stage chunk: issue all loads first (one HBM latency), then pack+write
        float4 px[12];
        #pragma unroll
        for (int w2 = 0; w2 < CH / 2; ++w2) {
            int t = t0 + 2 * w2 + s2;
            t = (t < T_LEN) ? t : (T_LEN - 1);            // clamped, branchless
            const float* src = xbase + (size_t)t * D_DIM;
            px[2 * w2]     = *(const float4*)(src);
            px[2 * w2 + 1] = *(const float4*)(src + 4);
        }
        #pragma unroll
        for (int w2 = 0; w2 < CH / 2; ++w2) {
            const int s = 2 * w2 + s2;
            *(bf16x8*)&x_sm[swz(s * BM + srow, cs)] = pack8(px[2 * w2], px[2 * w2 + 1]);
        }
        if (tid < BM * CH) {
            int t = t0 + (tid >> 4);
            t = (t < T_LEN) ? t : (T_LEN - 1);
            a_sm[tid] = Att[(size_t)(b0 + (tid & 15)) * T_LEN + t];
        }
        __syncthreads();

        for (int s = 0; s < L; ++s) {
            // ---------- phase A: B-frag loads + GEMM1 + GEMM2 x-part ----------
            bf16x8 hf[4], xf[4];
            #pragma unroll
            for (int kt = 0; kt < 4; ++kt) {
                hf[kt] = *(const bf16x8*)&h_bf[swz(ln, 4 * kt + q)];
                xf[kt] = *(const bf16x8*)&x_sm[swz(s * BM + ln, 4 * kt + q)];
            }
            const float a_att = a_sm[s * BM + ln];

            f32x4 accr1 = (f32x4)0.0f, accr2 = (f32x4)0.0f;
            f32x4 accu1 = (f32x4)0.0f, accu2 = (f32x4)0.0f;
            f32x4 acch  = (f32x4)0.0f;
            // r first: its result gates the barrier
            #pragma unroll
            for (int kt = 0; kt < 4; ++kt) {
                accr1 = __builtin_amdgcn_mfma_f32_16x16x32_bf16(wr[kt],     hf[kt], accr1, 0, 0, 0);
                accr2 = __builtin_amdgcn_mfma_f32_16x16x32_bf16(wr[kt + 4], xf[kt], accr2, 0, 0, 0);
            }
            #pragma unroll
            for (int kt = 0; kt < 4; ++kt) {
                acch  = __builtin_amdgcn_mfma_f32_16x16x32_bf16(wh[kt],     xf[kt], acch,  0, 0, 0);
                accu1 = __builtin_amdgcn_mfma_f32_16x16x32_bf16(wu[kt],     hf[kt], accu1, 0, 0, 0);
                accu2 = __builtin_amdgcn_mfma_f32_16x16x32_bf16(wu[kt + 4], xf[kt], accu2, 0, 0, 0);
            }

            // ---------- phase B: r sigmoid; r*h -> LDS (b64, 4 packed bf16) ----------
            {
                float rh[4];
                #pragma unroll
                for (int r = 0; r < 4; ++r) {
                    float zr = accr1[r] + accr2[r] + nbr[r];   // = -z_r/ln2
                    float rv = fast_rcp(1.0f + fast_exp2(zr)); // sigmoid
                    rh[r] = rv * hreg[r];
                }
                uint2 wv; wv.x = pkbf2(rh[0], rh[1]); wv.y = pkbf2(rh[2], rh[3]);
                const int c8 = 2 * wave + (q >> 1);            // chunk of gatecol base 16w+4q
                *(uint2*)&rh_bf[ln * 128 + ((c8 ^ (ln & 7)) << 3) + (q & 1) * 4] = wv;
            }
            __syncthreads();   // rh handoff

            // ---------- phase C: GEMM2 rh-part; u-gate sigmoid overlaps MFMA ----------
            bf16x8 rf[4];
            #pragma unroll
            for (int kt = 0; kt < 4; ++kt)
                rf[kt] = *(const bf16x8*)&rh_bf[swz(ln, 4 * kt + q)];

            float uq[4];
            #pragma unroll
            for (int r = 0; r < 4; ++r) {
                float zu = accu1[r] + accu2[r] + nbu[r];       // = -z_u/ln2
                float u  = fast_rcp(1.0f + fast_exp2(zu));     // sigmoid
                uq[r] = u * a_att;                             // attention-modulated
            }
            #pragma unroll
            for (int kt = 0; kt < 4; ++kt)
                acch = __builtin_amdgcn_mfma_f32_16x16x32_bf16(wh[kt + 4], rf[kt], acch, 0, 0, 0);

            // ---------- phase D: tanh, h update (fp32 regs), publish h (b64) ----------
            #pragma unroll
            for (int r = 0; r < 4; ++r) {
                float z  = acch[r] + bh2[r];                        // = 2*z_h/ln2
                float hh = 1.0f - 2.0f * fast_rcp(1.0f + fast_exp2(z)); // tanh
                float ho = hreg[r];
                hreg[r] = ho + uq[r] * (hh - ho);                   // u*hh + (1-u)*h
            }
            {
                uint2 wv; wv.x = pkbf2(hreg[0], hreg[1]); wv.y = pkbf2(hreg[2], hreg[3]);
                const int c8 = 2 * wave + (q >> 1);
                *(uint2*)&h_bf[ln * 128 + ((c8 ^ (ln & 7)) << 3) + (q & 1) * 4] = wv;
            }
            __syncthreads();   // h handoff to next step / chunk restage
        }
        t0 += CH;
    }

    // ---- store h_final: 4 consecutive gatecols per thread -> dwordx4 ----
    {
        f32x4 v;
        #pragma unroll
        for (int r = 0; r < 4; ++r) v[r] = hreg[r];
        *(f32x4*)&out[(size_t)(b0 + ln) * U_DIM + 16 * wave + 4 * q] = v;
    }
}

extern "C" void kernel_launch(void* const* d_in, const int* in_sizes, int n_in,
                              void* d_out, int out_size, void* d_ws, size_t ws_size,
                              hipStream_t stream) {
    const float* X   = (const float*)d_in[0];
    const float* Att = (const float*)d_in[1];
    const float* Wu  = (const float*)d_in[2];
    const float* bu  = (const float*)d_in[3];
    const float* Wr  = (const float*)d_in[4];
    const float* br  = (const float*)d_in[5];
    const float* Wh  = (const float*)d_in[6];
    const float* bh  = (const float*)d_in[7];
    float* out = (float*)d_out;

    gru_scan_kernel<<<dim3(2048 / BM), dim3(512), 0, stream>>>(
        X, Att, Wu, bu, Wr, br, Wh, bh, out);
}

// Round 8
// 457.235 us; speedup vs baseline: 1.3518x; 1.0703x over previous
//
#include <hip/hip_runtime.h>
#include <hip/hip_bf16.h>

// InterestEvolve: attention-modulated GRU scan. B=2048, T=200, D=128, U=128.
//
// R8 = R7 + the actual NaN fix: the K-major padded LDS buffers are
// XSTEP=2176 ushorts (1088 uints) but R6/R7 only zeroed 1024 uints —
// kchunk 15 of h_bf read uninitialized LDS at step 0 (NaN/Inf garbage
// propagated through r*h). Grid-stride clear of the full buffers.
// Everything else identical to R7: K-major padded LDS (KCS=136, conflict-free
// b128 reads AND staged writes), bias preloaded into MFMA C operand,
// v_cvt_pk_bf16_f32 packing, 2+2 split critical chains, within-chunk x-part
// MFMA pipelining, synchronous chunk staging.
// 128 blocks x 512 threads (8 waves, 2/SIMD); wave owns 16 gatecols.

#define T_LEN 200
#define D_DIM 128
#define U_DIM 128
#define BM    16
#define CH    12
#define KCS   136          // ushorts per kchunk slot-row: 16 batch*8 + 8 pad
#define XSTEP (16 * KCS)   // ushorts per staged step (2176)

typedef __attribute__((ext_vector_type(8))) short bf16x8;
typedef __attribute__((ext_vector_type(4))) float f32x4;
typedef __attribute__((ext_vector_type(4))) unsigned int uint4v;

static __device__ __forceinline__ unsigned short f2bf(float f) {
    unsigned int u = __builtin_bit_cast(unsigned int, f);
    u += 0x7fffu + ((u >> 16) & 1u);       // round-to-nearest-even
    return (unsigned short)(u >> 16);
}
static __device__ __forceinline__ unsigned int pkbf2(float a, float b) {
    float2 t; t.x = a; t.y = b;
    __hip_bfloat162 v = __float22bfloat162_rn(t);   // v_cvt_pk_bf16_f32
    unsigned int u; __builtin_memcpy(&u, &v, 4);
    return u;
}
static __device__ __forceinline__ uint4v pack8u(float4 lo, float4 hi) {
    uint4v v;
    v[0] = pkbf2(lo.x, lo.y); v[1] = pkbf2(lo.z, lo.w);
    v[2] = pkbf2(hi.x, hi.y); v[3] = pkbf2(hi.z, hi.w);
    return v;
}
static __device__ __forceinline__ float fast_exp2(float x) {
#if __has_builtin(__builtin_amdgcn_exp2f)
    return __builtin_amdgcn_exp2f(x);
#else
    return exp2f(x);
#endif
}
static __device__ __forceinline__ float fast_rcp(float x) {
#if __has_builtin(__builtin_amdgcn_rcpf)
    return __builtin_amdgcn_rcpf(x);
#else
    return 1.0f / x;
#endif
}

__global__ __launch_bounds__(512, 2)
void gru_scan_kernel(const float* __restrict__ X,    // (B,T,D)
                     const float* __restrict__ Att,  // (B,T,1)
                     const float* __restrict__ Wu, const float* __restrict__ bu,
                     const float* __restrict__ Wr, const float* __restrict__ br,
                     const float* __restrict__ Wh, const float* __restrict__ bh,
                     float* __restrict__ out)        // (B,U)
{
    __shared__ __align__(16) unsigned short x_sm[CH * XSTEP];  // 52224 B
    __shared__ __align__(16) unsigned short h_bf[XSTEP];       // 4352 B
    __shared__ __align__(16) unsigned short rh_bf[XSTEP];      // 4352 B
    __shared__ float a_sm[CH * BM];                            // 768 B

    const int tid  = threadIdx.x;
    const int wave = tid >> 6;    // owns gatecols [16*wave, 16*wave+16)
    const int lane = tid & 63;
    const int q    = lane >> 4;
    const int ln   = lane & 15;
    const int b0   = blockIdx.x * BM;

    const float INVLN2 = 1.4426950408889634f;

    // ---- Weight A-fragments (16 gatecols per wave), bf16, ln2-prescaled.
    // lane holds gatecol m = ln (tile base 16*wave), k = 32*kt + 8*q + j.
    // GEMM1 k: [h|x] rows of Wu/Wr. GEMM2 k: [x | r*h] rows of Wh.
    bf16x8 wu[8], wr[8], wh[8];
    f32x4 nbu, nbr, bh2;   // biases for gatecols 16w+4q+0..3 (C-operand preload)
    {
        const int tb = 16 * wave;
        const int c  = tb + ln;
        const f32x4 bu4 = *(const f32x4*)&bu[tb + 4 * q];
        const f32x4 br4 = *(const f32x4*)&br[tb + 4 * q];
        const f32x4 bh4 = *(const f32x4*)&bh[tb + 4 * q];
        #pragma unroll
        for (int r = 0; r < 4; ++r) {
            nbu[r] = -bu4[r] * INVLN2;
            nbr[r] = -br4[r] * INVLN2;
            bh2[r] = 2.0f * bh4[r] * INVLN2;
        }
        #pragma unroll
        for (int kt = 0; kt < 8; ++kt) {
            const int k0 = 32 * kt + 8 * q;
            bf16x8 vu, vr, vh;
            #pragma unroll
            for (int j = 0; j < 8; ++j) {
                vu[j] = (short)f2bf(Wu[(k0 + j) * U_DIM + c] * -INVLN2);
                vr[j] = (short)f2bf(Wr[(k0 + j) * U_DIM + c] * -INVLN2);
                vh[j] = (short)f2bf(Wh[(k0 + j) * U_DIM + c] * (2.0f * INVLN2));
            }
            wu[kt] = vu; wr[kt] = vr; wh[kt] = vh;
        }
    }

    float hreg[4] = {0.f, 0.f, 0.f, 0.f};   // fp32 h: batch=ln, gatecol=16w+4q+r

    // ---- FIX: clear ALL of h_bf / rh_bf (1088 uints each, incl. padding) ----
    {
        unsigned int* hz = (unsigned int*)h_bf;
        unsigned int* rz = (unsigned int*)rh_bf;
        for (int i = tid; i < XSTEP / 2; i += 512) { hz[i] = 0; rz[i] = 0; }
    }

    // staging map: thread = (s2 = tid>>8, srow = (tid>>4)&15, cs = tid&15)
    const int s2   = tid >> 8;
    const int srow = (tid >> 4) & 15;
    const int cs   = tid & 15;
    const float* xbase = X + (size_t)(b0 + srow) * T_LEN * D_DIM + cs * 8;

    int t0 = 0;
    for (int ch = 0; ch < (T_LEN + CH - 1) / CH; ++ch) {
        const int L = (t0 + CH <= T_LEN) ? CH : (T_LEN - t0);

        // ---- stage chunk synchronously: issue all loads, then pack+write ----
        {
            float4 px[12];
            #pragma unroll
            for (int w2 = 0; w2 < CH / 2; ++w2) {
                int t = t0 + 2 * w2 + s2;
                t = (t < T_LEN) ? t : (T_LEN - 1);           // clamped, branchless
                const float* src = xbase + (size_t)t * D_DIM;
                px[2 * w2]     = *(const float4*)(src);
                px[2 * w2 + 1] = *(const float4*)(src + 4);
            }
            float a_px = 0.0f;
            if (tid < BM * CH) {
                int t = t0 + (tid >> 4);
                t = (t < T_LEN) ? t : (T_LEN - 1);
                a_px = Att[(size_t)(b0 + (tid & 15)) * T_LEN + t];
            }
            #pragma unroll
            for (int w2 = 0; w2 < CH / 2; ++w2) {
                const int s = 2 * w2 + s2;
                *(uint4v*)&x_sm[s * XSTEP + cs * KCS + srow * 8] =
                    pack8u(px[2 * w2], px[2 * w2 + 1]);
            }
            if (tid < BM * CH) a_sm[tid] = a_px;
        }
        __syncthreads();

        // ---- x-part accumulators for step 0 (bias preloaded into C) ----
        f32x4 acc_r, acc_u, acc_h;
        {
            bf16x8 xf[4];
            #pragma unroll
            for (int kt = 0; kt < 4; ++kt)
                xf[kt] = *(const bf16x8*)&x_sm[(4 * kt + q) * KCS + ln * 8];
            acc_r = nbr; acc_u = nbu; acc_h = bh2;
            #pragma unroll
            for (int kt = 0; kt < 4; ++kt) {
                acc_r = __builtin_amdgcn_mfma_f32_16x16x32_bf16(wr[kt + 4], xf[kt], acc_r, 0, 0, 0);
                acc_u = __builtin_amdgcn_mfma_f32_16x16x32_bf16(wu[kt + 4], xf[kt], acc_u, 0, 0, 0);
                acc_h = __builtin_amdgcn_mfma_f32_16x16x32_bf16(wh[kt],     xf[kt], acc_h, 0, 0, 0);
            }
        }

        for (int s = 0; s < L; ++s) {
            // ---------- region 1: h-parts (r critical, 2+2 split) ----------
            bf16x8 hf[4];
            #pragma unroll
            for (int kt = 0; kt < 4; ++kt)
                hf[kt] = *(const bf16x8*)&h_bf[(4 * kt + q) * KCS + ln * 8];
            const float a_att = a_sm[s * BM + ln];

            f32x4 ra = acc_r, rb = (f32x4)0.0f;
            ra = __builtin_amdgcn_mfma_f32_16x16x32_bf16(wr[0], hf[0], ra, 0, 0, 0);
            rb = __builtin_amdgcn_mfma_f32_16x16x32_bf16(wr[2], hf[2], rb, 0, 0, 0);
            ra = __builtin_amdgcn_mfma_f32_16x16x32_bf16(wr[1], hf[1], ra, 0, 0, 0);
            rb = __builtin_amdgcn_mfma_f32_16x16x32_bf16(wr[3], hf[3], rb, 0, 0, 0);
            #pragma unroll
            for (int kt = 0; kt < 4; ++kt)
                acc_u = __builtin_amdgcn_mfma_f32_16x16x32_bf16(wu[kt], hf[kt], acc_u, 0, 0, 0);

            {   // r sigmoid; r*h -> LDS (one ds_write_b64)
                float rh[4];
                #pragma unroll
                for (int r = 0; r < 4; ++r) {
                    float zr = ra[r] + rb[r];                   // = -z_r/ln2
                    float rv = fast_rcp(1.0f + fast_exp2(zr));  // sigmoid
                    rh[r] = rv * hreg[r];
                }
                uint2 wv; wv.x = pkbf2(rh[0], rh[1]); wv.y = pkbf2(rh[2], rh[3]);
                const int c8 = 2 * wave + (q >> 1);
                *(uint2*)&rh_bf[c8 * KCS + ln * 8 + (q & 1) * 4] = wv;
            }
            __syncthreads();   // rh handoff

            // ---------- region 2 ----------
            bf16x8 rf[4];
            #pragma unroll
            for (int kt = 0; kt < 4; ++kt)
                rf[kt] = *(const bf16x8*)&rh_bf[(4 * kt + q) * KCS + ln * 8];

            // u gate (off critical path)
            float uq[4];
            #pragma unroll
            for (int r = 0; r < 4; ++r) {
                float u = fast_rcp(1.0f + fast_exp2(acc_u[r]));  // sigmoid (-z/ln2 form)
                uq[r] = u * a_att;
            }

            // candidate: rh-part (critical, 2+2 split)
            f32x4 ha = acc_h, hb = (f32x4)0.0f;
            ha = __builtin_amdgcn_mfma_f32_16x16x32_bf16(wh[4], rf[0], ha, 0, 0, 0);
            hb = __builtin_amdgcn_mfma_f32_16x16x32_bf16(wh[6], rf[2], hb, 0, 0, 0);
            ha = __builtin_amdgcn_mfma_f32_16x16x32_bf16(wh[5], rf[1], ha, 0, 0, 0);
            hb = __builtin_amdgcn_mfma_f32_16x16x32_bf16(wh[7], rf[3], hb, 0, 0, 0);

            // tanh, h update, publish h
            #pragma unroll
            for (int r = 0; r < 4; ++r) {
                float z  = ha[r] + hb[r];                               // = 2*z_h/ln2
                float hh = 1.0f - 2.0f * fast_rcp(1.0f + fast_exp2(z)); // tanh
                float ho = hreg[r];
                hreg[r] = ho + uq[r] * (hh - ho);                       // u*hh + (1-u)*h
            }
            {
                uint2 wv; wv.x = pkbf2(hreg[0], hreg[1]); wv.y = pkbf2(hreg[2], hreg[3]);
                const int c8 = 2 * wave + (q >> 1);
                *(uint2*)&h_bf[c8 * KCS + ln * 8 + (q & 1) * 4] = wv;
            }

            // x-part accumulators for step s+1 (same chunk, off critical path)
            if (s + 1 < L) {
                bf16x8 xf[4];
                #pragma unroll
                for (int kt = 0; kt < 4; ++kt)
                    xf[kt] = *(const bf16x8*)&x_sm[(s + 1) * XSTEP + (4 * kt + q) * KCS + ln * 8];
                acc_r = nbr; acc_u = nbu; acc_h = bh2;
                #pragma unroll
                for (int kt = 0; kt < 4; ++kt) {
                    acc_r = __builtin_amdgcn_mfma_f32_16x16x32_bf16(wr[kt + 4], xf[kt], acc_r, 0, 0, 0);
                    acc_u = __builtin_amdgcn_mfma_f32_16x16x32_bf16(wu[kt + 4], xf[kt], acc_u, 0, 0, 0);
                    acc_h = __builtin_amdgcn_mfma_f32_16x16x32_bf16(wh[kt],     xf[kt], acc_h, 0, 0, 0);
                }
            }
            __syncthreads();   // h handoff
        }
        t0 += CH;
    }

    // ---- store h_final: 4 consecutive gatecols per thread -> dwordx4 ----
    {
        f32x4 v;
        #pragma unroll
        for (int r = 0; r < 4; ++r) v[r] = hreg[r];
        *(f32x4*)&out[(size_t)(b0 + ln) * U_DIM + 16 * wave + 4 * q] = v;
    }
}

extern "C" void kernel_launch(void* const* d_in, const int* in_sizes, int n_in,
                              void* d_out, int out_size, void* d_ws, size_t ws_size,
                              hipStream_t stream) {
    const float* X   = (const float*)d_in[0];
    const float* Att = (const float*)d_in[1];
    const float* Wu  = (const float*)d_in[2];
    const float* bu  = (const float*)d_in[3];
    const float* Wr  = (const float*)d_in[4];
    const float* br  = (const float*)d_in[5];
    const float* Wh  = (const float*)d_in[6];
    const float* bh  = (const float*)d_in[7];
    float* out = (float*)d_out;

    gru_scan_kernel<<<dim3(2048 / BM), dim3(512), 0, stream>>>(
        X, Att, Wu, bu, Wr, br, Wh, bh, out);
}